// Round 1
// baseline (2916.170 us; speedup 1.0000x reference)
//
#include <hip/hip_runtime.h>

// ---------------------------------------------------------------------------
// MORAL 2-layer GCN on MI355X.
// Pipeline:
//   1. column min/max of features (encoded-uint atomics)
//   2. prep: W1p = s*W1, c = (mn*s) @ W1 ; czero = 0
//   3. deg count (int atomics over edge dst) ; dinv = rsqrt(deg+1)
//   4. gemm1: g = (x @ W1p - c) * dinv[row]  (stores g AND acc-init = self loop)
//   5. scatter1: acc[dst] += g[src]   (float atomics, wave/edge)
//   6. finalize1: out1 = relu(dinv*acc + b1)  in place
//   7. gemm2: g = (out1 @ W2) * dinv ; acc2-init -> d_out
//   8. scatter2: d_out[dst] += g[src]
//   9. finalize2: d_out = dinv*d_out + b2
// ---------------------------------------------------------------------------

__device__ __forceinline__ unsigned encf(float f) {
  unsigned u = __float_as_uint(f);
  return (u & 0x80000000u) ? ~u : (u | 0x80000000u);
}
__device__ __forceinline__ float decf(unsigned e) {
  unsigned u = (e & 0x80000000u) ? (e ^ 0x80000000u) : ~e;
  return __uint_as_float(u);
}

// edges may arrive as int32 or int64 (JAX x64 flag unknown). Detect on device.
__global__ void detect_kernel(const int* __restrict__ edges, int E, int* flag64) {
  if (threadIdx.x == 0 && blockIdx.x == 0) {
    int n = (2 * E < 256) ? 2 * E : 256;
    int all_odd_zero = 1;
    for (int i = 1; i < n; i += 2)
      if (edges[i] != 0) { all_odd_zero = 0; break; }
    *flag64 = all_odd_zero;  // int64 values < 2^31 -> high words all zero
  }
}

__device__ __forceinline__ void load_edge(const void* edges, int E, int e,
                                          int is64, int& s, int& d) {
  if (is64) {
    const long long* p = (const long long*)edges;
    s = (int)p[e]; d = (int)p[E + e];
  } else {
    const int* p = (const int*)edges;
    s = p[e]; d = p[E + e];
  }
}

__global__ void init_kernel(unsigned* minenc, unsigned* maxenc, int* deg, int N) {
  int i = blockIdx.x * blockDim.x + threadIdx.x;
  if (i < 128) { minenc[i] = 0xFFFFFFFFu; maxenc[i] = 0u; }
  if (i < N) deg[i] = 0;
}

__global__ void colminmax_kernel(const float* __restrict__ x, unsigned* minenc,
                                 unsigned* maxenc, int N) {
  int g = blockIdx.x * blockDim.x + threadIdx.x;
  int col = g & 127;
  int r0 = g >> 7;
  int nstream = (gridDim.x * blockDim.x) >> 7;
  float mn = 3.4e38f, mx = -3.4e38f;
  for (int r = r0; r < N; r += nstream) {
    float v = x[(size_t)r * 128 + col];
    mn = fminf(mn, v); mx = fmaxf(mx, v);
  }
  atomicMin(&minenc[col], encf(mn));
  atomicMax(&maxenc[col], encf(mx));
}

__global__ void prep_kernel(const unsigned* __restrict__ minenc,
                            const unsigned* __restrict__ maxenc,
                            const float* __restrict__ W1, float* __restrict__ W1p,
                            float* __restrict__ cvec, float* __restrict__ czero) {
  __shared__ float mn_s[128], s_s[128];
  int j = threadIdx.x;
  float mn = decf(minenc[j]);
  float mx = decf(maxenc[j]);
  float denom = (mx > mn) ? (mx - mn) : 1.0f;
  mn_s[j] = mn; s_s[j] = 1.0f / denom;
  __syncthreads();
  float c = 0.f;
  for (int k = 0; k < 128; ++k) {
    float wp = s_s[k] * W1[k * 128 + j];
    W1p[k * 128 + j] = wp;
    c += mn_s[k] * wp;
  }
  cvec[j] = c;
  czero[j] = 0.f;
}

__global__ void deg_kernel(const void* __restrict__ edges, int E,
                           const int* __restrict__ flag64, int* __restrict__ deg) {
  int e = blockIdx.x * blockDim.x + threadIdx.x;
  if (e >= E) return;
  int is64 = *flag64;
  int s, d;
  load_edge(edges, E, e, is64, s, d);
  atomicAdd(&deg[d], 1);
}

__global__ void dinv_kernel(const int* __restrict__ deg, float* __restrict__ dinv, int N) {
  int i = blockIdx.x * blockDim.x + threadIdx.x;
  if (i < N) dinv[i] = rsqrtf((float)deg[i] + 1.0f);  // +1 = self loop
}

// C = (X @ W - cvec) * dinv[row], stored to BOTH g and acc (acc init = self loop)
__global__ __launch_bounds__(256) void gemm_kernel(
    const float* __restrict__ X, const float* __restrict__ W,
    const float* __restrict__ cvec, const float* __restrict__ dinv,
    float* __restrict__ g, float* __restrict__ acc, int N) {
  __shared__ float xs[64][33];
  __shared__ float ws[32][128];
  int t = threadIdx.x;
  int tx = t & 31;        // col group: cols tx*4 .. tx*4+3
  int ty = t >> 5;        // row group: rows ty*8 .. ty*8+7
  int rowbase = blockIdx.x * 64;
  float a[8][4];
#pragma unroll
  for (int r = 0; r < 8; ++r)
#pragma unroll
    for (int c = 0; c < 4; ++c) a[r][c] = 0.f;

  for (int k0 = 0; k0 < 128; k0 += 32) {
    __syncthreads();
#pragma unroll
    for (int i = 0; i < 8; ++i) {
      int e = i * 256 + t;
      int r = e >> 5, kk = e & 31;
      int row = rowbase + r;
      xs[r][kk] = (row < N) ? X[(size_t)row * 128 + k0 + kk] : 0.f;
    }
#pragma unroll
    for (int i = 0; i < 16; ++i) {
      int e = i * 256 + t;
      int kk = e >> 7, j = e & 127;
      ws[kk][j] = W[(k0 + kk) * 128 + j];
    }
    __syncthreads();
#pragma unroll
    for (int kk = 0; kk < 32; ++kk) {
      float4 wv = *(const float4*)&ws[kk][tx * 4];
#pragma unroll
      for (int r = 0; r < 8; ++r) {
        float xv = xs[ty * 8 + r][kk];
        a[r][0] += xv * wv.x;
        a[r][1] += xv * wv.y;
        a[r][2] += xv * wv.z;
        a[r][3] += xv * wv.w;
      }
    }
  }
  float4 cv = *(const float4*)&cvec[tx * 4];
#pragma unroll
  for (int r = 0; r < 8; ++r) {
    int row = rowbase + ty * 8 + r;
    if (row < N) {
      float dv = dinv[row];
      float4 o;
      o.x = (a[r][0] - cv.x) * dv;
      o.y = (a[r][1] - cv.y) * dv;
      o.z = (a[r][2] - cv.z) * dv;
      o.w = (a[r][3] - cv.w) * dv;
      *(float4*)&g[(size_t)row * 128 + tx * 4] = o;
      *(float4*)&acc[(size_t)row * 128 + tx * 4] = o;
    }
  }
}

// one 64-lane wave per edge; each lane handles 2 columns
__global__ __launch_bounds__(256) void scatter_kernel(
    const void* __restrict__ edges, int E, const int* __restrict__ flag64,
    const float* __restrict__ g, float* __restrict__ acc) {
  int gid = blockIdx.x * blockDim.x + threadIdx.x;
  int e = gid >> 6;
  if (e >= E) return;
  int lane = gid & 63;
  int is64 = *flag64;
  int s, d;
  load_edge(edges, E, e, is64, s, d);
  float2 v = *(const float2*)&g[(size_t)s * 128 + lane * 2];
  atomicAdd(&acc[(size_t)d * 128 + lane * 2], v.x);
  atomicAdd(&acc[(size_t)d * 128 + lane * 2 + 1], v.y);
}

__global__ void finalize_kernel(float* __restrict__ acc, const float* __restrict__ dinv,
                                const float* __restrict__ b, int N, int dorelu) {
  int i = blockIdx.x * blockDim.x + threadIdx.x;  // over N*32 float4s
  if (i >= N * 32) return;
  int n = i >> 5;
  int j4 = (i & 31) * 4;
  float dv = dinv[n];
  float4 v = *(float4*)&acc[(size_t)i * 4];
  float4 bb = *(const float4*)&b[j4];
  v.x = dv * v.x + bb.x;
  v.y = dv * v.y + bb.y;
  v.z = dv * v.z + bb.z;
  v.w = dv * v.w + bb.w;
  if (dorelu) {
    v.x = fmaxf(v.x, 0.f);
    v.y = fmaxf(v.y, 0.f);
    v.z = fmaxf(v.z, 0.f);
    v.w = fmaxf(v.w, 0.f);
  }
  *(float4*)&acc[(size_t)i * 4] = v;
}

extern "C" void kernel_launch(void* const* d_in, const int* in_sizes, int n_in,
                              void* d_out, int out_size, void* d_ws, size_t ws_size,
                              hipStream_t stream) {
  const float* features = (const float*)d_in[0];
  const float* W1 = (const float*)d_in[1];
  const float* b1 = (const float*)d_in[2];
  const float* W2 = (const float*)d_in[3];
  const float* b2 = (const float*)d_in[4];
  const void* edges = d_in[5];
  const int N = in_sizes[0] / 128;
  const int E = in_sizes[5] / 2;

  float* ws = (float*)d_ws;
  size_t off = 0;
  float* gbuf = ws + off;   off += (size_t)N * 128;
  float* accbuf = ws + off; off += (size_t)N * 128;
  int* deg = (int*)(ws + off);       off += N;
  float* dinv = ws + off;            off += N;
  unsigned* minenc = (unsigned*)(ws + off); off += 128;
  unsigned* maxenc = (unsigned*)(ws + off); off += 128;
  float* W1p = ws + off;  off += 128 * 128;
  float* cvec = ws + off; off += 128;
  float* czero = ws + off; off += 128;
  int* flag64 = (int*)(ws + off); off += 1;
  float* outf = (float*)d_out;

  detect_kernel<<<1, 1, 0, stream>>>((const int*)edges, E, flag64);
  init_kernel<<<(N + 255) / 256, 256, 0, stream>>>(minenc, maxenc, deg, N);
  colminmax_kernel<<<512, 256, 0, stream>>>(features, minenc, maxenc, N);
  deg_kernel<<<(E + 255) / 256, 256, 0, stream>>>(edges, E, flag64, deg);
  prep_kernel<<<1, 128, 0, stream>>>(minenc, maxenc, W1, W1p, cvec, czero);
  dinv_kernel<<<(N + 255) / 256, 256, 0, stream>>>(deg, dinv, N);

  // layer 1
  gemm_kernel<<<(N + 63) / 64, 256, 0, stream>>>(features, W1p, cvec, dinv, gbuf, accbuf, N);
  scatter_kernel<<<(E * 64 + 255) / 256, 256, 0, stream>>>(edges, E, flag64, gbuf, accbuf);
  finalize_kernel<<<(N * 32 + 255) / 256, 256, 0, stream>>>(accbuf, dinv, b1, N, 1);

  // layer 2
  gemm_kernel<<<(N + 63) / 64, 256, 0, stream>>>(accbuf, W2, czero, dinv, gbuf, outf, N);
  scatter_kernel<<<(E * 64 + 255) / 256, 256, 0, stream>>>(edges, E, flag64, gbuf, outf);
  finalize_kernel<<<(N * 32 + 255) / 256, 256, 0, stream>>>(outf, dinv, b2, N, 0);
}

// Round 2
// 661.736 us; speedup vs baseline: 4.4068x; 4.4068x over previous
//
#include <hip/hip_runtime.h>

// ---------------------------------------------------------------------------
// MORAL 2-layer GCN on MI355X — round 2: CSR pull-gather instead of atomics.
// Pipeline:
//   1. column min/max of features (encoded-uint atomics)
//   2. prep: W1p = s*W1, c = (mn*s) @ W1 ; czero = 0
//   3. deg count (int atomics over edge dst) ; dinv = rsqrt(deg+1)
//   4. prefix-scan deg -> rowptr ; cursor fill -> adj  (CSR, built once)
//   5. gemm1: g = (x @ W1p - c) * dinv[row]
//   6. agg1:  h1[d] = relu(dinv[d]*(g[d] + sum_{s in adj[d]} g[s]) + b1)
//             (h1 lives in d_out as scratch)
//   7. gemm2: g = (h1 @ W2) * dinv
//   8. agg2:  d_out[d] = dinv[d]*(g[d] + sum g[s]) + b2
// ---------------------------------------------------------------------------

__device__ __forceinline__ unsigned encf(float f) {
  unsigned u = __float_as_uint(f);
  return (u & 0x80000000u) ? ~u : (u | 0x80000000u);
}
__device__ __forceinline__ float decf(unsigned e) {
  unsigned u = (e & 0x80000000u) ? (e ^ 0x80000000u) : ~e;
  return __uint_as_float(u);
}

// edges may arrive as int32 or int64 (JAX x64 flag unknown). Detect on device.
__global__ void detect_kernel(const int* __restrict__ edges, int E, int* flag64) {
  if (threadIdx.x == 0 && blockIdx.x == 0) {
    int n = (2 * E < 256) ? 2 * E : 256;
    int all_odd_zero = 1;
    for (int i = 1; i < n; i += 2)
      if (edges[i] != 0) { all_odd_zero = 0; break; }
    *flag64 = all_odd_zero;  // int64 values < 2^31 -> high words all zero
  }
}

__device__ __forceinline__ void load_edge(const void* edges, int E, int e,
                                          int is64, int& s, int& d) {
  if (is64) {
    const long long* p = (const long long*)edges;
    s = (int)p[e]; d = (int)p[E + e];
  } else {
    const int* p = (const int*)edges;
    s = p[e]; d = p[E + e];
  }
}

__global__ void init_kernel(unsigned* minenc, unsigned* maxenc, int* deg, int N) {
  int i = blockIdx.x * blockDim.x + threadIdx.x;
  if (i < 128) { minenc[i] = 0xFFFFFFFFu; maxenc[i] = 0u; }
  if (i < N) deg[i] = 0;
}

__global__ void colminmax_kernel(const float* __restrict__ x, unsigned* minenc,
                                 unsigned* maxenc, int N) {
  int g = blockIdx.x * blockDim.x + threadIdx.x;
  int col = g & 127;
  int r0 = g >> 7;
  int nstream = (gridDim.x * blockDim.x) >> 7;
  float mn = 3.4e38f, mx = -3.4e38f;
  for (int r = r0; r < N; r += nstream) {
    float v = x[(size_t)r * 128 + col];
    mn = fminf(mn, v); mx = fmaxf(mx, v);
  }
  atomicMin(&minenc[col], encf(mn));
  atomicMax(&maxenc[col], encf(mx));
}

__global__ void prep_kernel(const unsigned* __restrict__ minenc,
                            const unsigned* __restrict__ maxenc,
                            const float* __restrict__ W1, float* __restrict__ W1p,
                            float* __restrict__ cvec, float* __restrict__ czero) {
  __shared__ float mn_s[128], s_s[128];
  int j = threadIdx.x;
  float mn = decf(minenc[j]);
  float mx = decf(maxenc[j]);
  float denom = (mx > mn) ? (mx - mn) : 1.0f;
  mn_s[j] = mn; s_s[j] = 1.0f / denom;
  __syncthreads();
  float c = 0.f;
  for (int k = 0; k < 128; ++k) {
    float wp = s_s[k] * W1[k * 128 + j];
    W1p[k * 128 + j] = wp;
    c += mn_s[k] * wp;
  }
  cvec[j] = c;
  czero[j] = 0.f;
}

__global__ void deg_kernel(const void* __restrict__ edges, int E,
                           const int* __restrict__ flag64, int* __restrict__ deg) {
  int e = blockIdx.x * blockDim.x + threadIdx.x;
  if (e >= E) return;
  int is64 = *flag64;
  int s, d;
  load_edge(edges, E, e, is64, s, d);
  atomicAdd(&deg[d], 1);
}

__global__ void dinv_kernel(const int* __restrict__ deg, float* __restrict__ dinv, int N) {
  int i = blockIdx.x * blockDim.x + threadIdx.x;
  if (i < N) dinv[i] = rsqrtf((float)deg[i] + 1.0f);  // +1 = self loop
}

// ---- prefix scan: deg -> rowptr (exclusive) --------------------------------
#define SB 256

__global__ void scan1_kernel(const int* __restrict__ deg, int* __restrict__ rowptr,
                             int* __restrict__ bsum, int N) {
  __shared__ int tmp[SB];
  int i = blockIdx.x * SB + threadIdx.x;
  int v = (i < N) ? deg[i] : 0;
  tmp[threadIdx.x] = v;
  __syncthreads();
  for (int off = 1; off < SB; off <<= 1) {
    int t = (threadIdx.x >= off) ? tmp[threadIdx.x - off] : 0;
    __syncthreads();
    tmp[threadIdx.x] += t;
    __syncthreads();
  }
  if (i < N) rowptr[i] = tmp[threadIdx.x] - v;  // block-local exclusive
  if (threadIdx.x == 0) bsum[blockIdx.x] = tmp[SB - 1];
}

__global__ void scan2_kernel(int* __restrict__ bsum, int nb) {
  __shared__ int tmp[SB];
  int carry = 0;
  for (int base = 0; base < nb; base += SB) {
    int i = base + threadIdx.x;
    int v = (i < nb) ? bsum[i] : 0;
    tmp[threadIdx.x] = v;
    __syncthreads();
    for (int off = 1; off < SB; off <<= 1) {
      int t = (threadIdx.x >= off) ? tmp[threadIdx.x - off] : 0;
      __syncthreads();
      tmp[threadIdx.x] += t;
      __syncthreads();
    }
    if (i < nb) bsum[i] = carry + tmp[threadIdx.x] - v;  // exclusive
    carry += tmp[SB - 1];
    __syncthreads();
  }
}

__global__ void scan3_kernel(int* __restrict__ rowptr, const int* __restrict__ bsum,
                             int N, int E) {
  int i = blockIdx.x * SB + threadIdx.x;
  if (i < N) rowptr[i] += bsum[blockIdx.x];
  if (i == 0) rowptr[N] = E;
}

__global__ void cursor_kernel(const int* __restrict__ rowptr, int* __restrict__ cursor, int N) {
  int i = blockIdx.x * blockDim.x + threadIdx.x;
  if (i < N) cursor[i] = rowptr[i];
}

__global__ void fill_kernel(const void* __restrict__ edges, int E,
                            const int* __restrict__ flag64,
                            int* __restrict__ cursor, int* __restrict__ adj) {
  int e = blockIdx.x * blockDim.x + threadIdx.x;
  if (e >= E) return;
  int is64 = *flag64;
  int s, d;
  load_edge(edges, E, e, is64, s, d);
  int pos = atomicAdd(&cursor[d], 1);
  adj[pos] = s;
}

// ---- GEMM: g = (X @ W - cvec) * dinv[row] ----------------------------------
__global__ __launch_bounds__(256) void gemm_kernel(
    const float* __restrict__ X, const float* __restrict__ W,
    const float* __restrict__ cvec, const float* __restrict__ dinv,
    float* __restrict__ g, int N) {
  __shared__ float xs[64][33];
  __shared__ float ws[32][128];
  int t = threadIdx.x;
  int tx = t & 31;        // col group: cols tx*4 .. tx*4+3
  int ty = t >> 5;        // row group: rows ty*8 .. ty*8+7
  int rowbase = blockIdx.x * 64;
  float a[8][4];
#pragma unroll
  for (int r = 0; r < 8; ++r)
#pragma unroll
    for (int c = 0; c < 4; ++c) a[r][c] = 0.f;

  for (int k0 = 0; k0 < 128; k0 += 32) {
    __syncthreads();
#pragma unroll
    for (int i = 0; i < 8; ++i) {
      int e = i * 256 + t;
      int r = e >> 5, kk = e & 31;
      int row = rowbase + r;
      xs[r][kk] = (row < N) ? X[(size_t)row * 128 + k0 + kk] : 0.f;
    }
#pragma unroll
    for (int i = 0; i < 16; ++i) {
      int e = i * 256 + t;
      int kk = e >> 7, j = e & 127;
      ws[kk][j] = W[(k0 + kk) * 128 + j];
    }
    __syncthreads();
#pragma unroll
    for (int kk = 0; kk < 32; ++kk) {
      float4 wv = *(const float4*)&ws[kk][tx * 4];
#pragma unroll
      for (int r = 0; r < 8; ++r) {
        float xv = xs[ty * 8 + r][kk];
        a[r][0] += xv * wv.x;
        a[r][1] += xv * wv.y;
        a[r][2] += xv * wv.z;
        a[r][3] += xv * wv.w;
      }
    }
  }
  float4 cv = *(const float4*)&cvec[tx * 4];
#pragma unroll
  for (int r = 0; r < 8; ++r) {
    int row = rowbase + ty * 8 + r;
    if (row < N) {
      float dv = dinv[row];
      float4 o;
      o.x = (a[r][0] - cv.x) * dv;
      o.y = (a[r][1] - cv.y) * dv;
      o.z = (a[r][2] - cv.z) * dv;
      o.w = (a[r][3] - cv.w) * dv;
      *(float4*)&g[(size_t)row * 128 + tx * 4] = o;
    }
  }
}

// ---- aggregate: one wave per dst node, pull from CSR -----------------------
// out[d] = act(dinv[d] * (g[d] + sum_{s in adj[rowptr[d]..rowptr[d+1])} g[s]) + b)
__global__ __launch_bounds__(256) void aggregate_kernel(
    const int* __restrict__ rowptr, const int* __restrict__ adj,
    const float* __restrict__ g, const float* __restrict__ dinv,
    const float* __restrict__ b, float* __restrict__ out, int N, int dorelu) {
  int gid = blockIdx.x * blockDim.x + threadIdx.x;
  int d = gid >> 6;
  if (d >= N) return;
  int lane = gid & 63;
  int beg = rowptr[d], end = rowptr[d + 1];

  float2 sum = *(const float2*)&g[(size_t)d * 128 + lane * 2];  // self loop
  int i = beg;
  for (; i + 4 <= end; i += 4) {
    int s0 = adj[i], s1 = adj[i + 1], s2 = adj[i + 2], s3 = adj[i + 3];
    float2 v0 = *(const float2*)&g[(size_t)s0 * 128 + lane * 2];
    float2 v1 = *(const float2*)&g[(size_t)s1 * 128 + lane * 2];
    float2 v2 = *(const float2*)&g[(size_t)s2 * 128 + lane * 2];
    float2 v3 = *(const float2*)&g[(size_t)s3 * 128 + lane * 2];
    sum.x += (v0.x + v1.x) + (v2.x + v3.x);
    sum.y += (v0.y + v1.y) + (v2.y + v3.y);
  }
  for (; i < end; ++i) {
    int s = adj[i];
    float2 v = *(const float2*)&g[(size_t)s * 128 + lane * 2];
    sum.x += v.x; sum.y += v.y;
  }
  float dv = dinv[d];
  float2 bb = *(const float2*)&b[lane * 2];
  float2 o;
  o.x = dv * sum.x + bb.x;
  o.y = dv * sum.y + bb.y;
  if (dorelu) { o.x = fmaxf(o.x, 0.f); o.y = fmaxf(o.y, 0.f); }
  *(float2*)&out[(size_t)d * 128 + lane * 2] = o;
}

extern "C" void kernel_launch(void* const* d_in, const int* in_sizes, int n_in,
                              void* d_out, int out_size, void* d_ws, size_t ws_size,
                              hipStream_t stream) {
  const float* features = (const float*)d_in[0];
  const float* W1 = (const float*)d_in[1];
  const float* b1 = (const float*)d_in[2];
  const float* W2 = (const float*)d_in[3];
  const float* b2 = (const float*)d_in[4];
  const void* edges = d_in[5];
  const int N = in_sizes[0] / 128;
  const int E = in_sizes[5] / 2;
  const int NB = (N + SB - 1) / SB;

  float* ws = (float*)d_ws;
  size_t off = 0;
  float* gbuf = ws + off;              off += (size_t)N * 128;   // 51.2 MB
  int* rowptr = (int*)(ws + off);      off += N + 1;
  int* cursor = (int*)(ws + off);      off += N;
  int* adj = (int*)(ws + off);         off += E;                 // 6.4 MB
  int* deg = (int*)(ws + off);         off += N;
  float* dinv = ws + off;              off += N;
  int* bsum = (int*)(ws + off);        off += NB;
  unsigned* minenc = (unsigned*)(ws + off); off += 128;
  unsigned* maxenc = (unsigned*)(ws + off); off += 128;
  float* W1p = ws + off;               off += 128 * 128;
  float* cvec = ws + off;              off += 128;
  float* czero = ws + off;             off += 128;
  int* flag64 = (int*)(ws + off);      off += 1;

  float* outf = (float*)d_out;
  float* h1 = outf;  // layer-1 activations live in d_out (agg2 never reads d_out)

  // ---- graph prep (edge dtype, deg, CSR, dinv) ----
  detect_kernel<<<1, 1, 0, stream>>>((const int*)edges, E, flag64);
  init_kernel<<<(N + 255) / 256, 256, 0, stream>>>(minenc, maxenc, deg, N);
  colminmax_kernel<<<512, 256, 0, stream>>>(features, minenc, maxenc, N);
  deg_kernel<<<(E + 255) / 256, 256, 0, stream>>>(edges, E, flag64, deg);
  prep_kernel<<<1, 128, 0, stream>>>(minenc, maxenc, W1, W1p, cvec, czero);
  scan1_kernel<<<NB, SB, 0, stream>>>(deg, rowptr, bsum, N);
  scan2_kernel<<<1, SB, 0, stream>>>(bsum, NB);
  scan3_kernel<<<NB, SB, 0, stream>>>(rowptr, bsum, N, E);
  dinv_kernel<<<(N + 255) / 256, 256, 0, stream>>>(deg, dinv, N);
  cursor_kernel<<<(N + 255) / 256, 256, 0, stream>>>(rowptr, cursor, N);
  fill_kernel<<<(E + 255) / 256, 256, 0, stream>>>(edges, E, flag64, cursor, adj);

  // ---- layer 1 ----
  gemm_kernel<<<(N + 63) / 64, 256, 0, stream>>>(features, W1p, cvec, dinv, gbuf, N);
  aggregate_kernel<<<(N * 64 + 255) / 256, 256, 0, stream>>>(
      rowptr, adj, gbuf, dinv, b1, h1, N, 1);

  // ---- layer 2 ----
  gemm_kernel<<<(N + 63) / 64, 256, 0, stream>>>(h1, W2, czero, dinv, gbuf, N);
  aggregate_kernel<<<(N * 64 + 255) / 256, 256, 0, stream>>>(
      rowptr, adj, gbuf, dinv, b2, outf, N, 0);
}

// Round 3
// 436.535 us; speedup vs baseline: 6.6803x; 1.5159x over previous
//
#include <hip/hip_runtime.h>

// ---------------------------------------------------------------------------
// MORAL 2-layer GCN on MI355X — round 3: bf16 data plane + MFMA GEMMs.
//   g / h1 stored bf16 (halves gather traffic), GEMMs via mfma_f32_16x16x32_bf16,
//   aggregate = 2 dst nodes per wave (8B/lane gathers), CSR build unchanged.
// ---------------------------------------------------------------------------

typedef short bf16x8 __attribute__((ext_vector_type(8)));
typedef float f32x4 __attribute__((ext_vector_type(4)));
typedef unsigned short ushort_t;

__device__ __forceinline__ unsigned encf(float f) {
  unsigned u = __float_as_uint(f);
  return (u & 0x80000000u) ? ~u : (u | 0x80000000u);
}
__device__ __forceinline__ float decf(unsigned e) {
  unsigned u = (e & 0x80000000u) ? (e ^ 0x80000000u) : ~e;
  return __uint_as_float(u);
}
__device__ __forceinline__ ushort_t f2bf(float f) {
  unsigned u = __float_as_uint(f);
  u += 0x7FFF + ((u >> 16) & 1);  // RNE
  return (ushort_t)(u >> 16);
}
__device__ __forceinline__ float bf2f(ushort_t h) {
  return __uint_as_float((unsigned)h << 16);
}

// edges may arrive as int32 or int64 (JAX x64 flag unknown). Detect on device.
__global__ void detect_kernel(const int* __restrict__ edges, int E, int* flag64) {
  if (threadIdx.x == 0 && blockIdx.x == 0) {
    int n = (2 * E < 256) ? 2 * E : 256;
    int all_odd_zero = 1;
    for (int i = 1; i < n; i += 2)
      if (edges[i] != 0) { all_odd_zero = 0; break; }
    *flag64 = all_odd_zero;
  }
}

__device__ __forceinline__ void load_edge(const void* edges, int E, int e,
                                          int is64, int& s, int& d) {
  if (is64) {
    const long long* p = (const long long*)edges;
    s = (int)p[e]; d = (int)p[E + e];
  } else {
    const int* p = (const int*)edges;
    s = p[e]; d = p[E + e];
  }
}

__global__ void init_kernel(unsigned* minenc, unsigned* maxenc, int* deg, int N) {
  int i = blockIdx.x * blockDim.x + threadIdx.x;
  if (i < 128) { minenc[i] = 0xFFFFFFFFu; maxenc[i] = 0u; }
  if (i < N) deg[i] = 0;
}

__global__ void colminmax_kernel(const float* __restrict__ x, unsigned* minenc,
                                 unsigned* maxenc, int N) {
  int g = blockIdx.x * blockDim.x + threadIdx.x;
  int col = g & 127;
  int r0 = g >> 7;
  int nstream = (gridDim.x * blockDim.x) >> 7;
  float mn = 3.4e38f, mx = -3.4e38f;
  for (int r = r0; r < N; r += nstream) {
    float v = x[(size_t)r * 128 + col];
    mn = fminf(mn, v); mx = fmaxf(mx, v);
  }
  atomicMin(&minenc[col], encf(mn));
  atomicMax(&maxenc[col], encf(mx));
}

// Wt1[j][k] = bf16(s[k]*W1[k][j]); cvec[j] = sum_k mn[k]*float(Wt1[j][k])
// Wt2[j][k] = bf16(W2[k][j]); czero = 0
__global__ void prep_kernel(const unsigned* __restrict__ minenc,
                            const unsigned* __restrict__ maxenc,
                            const float* __restrict__ W1, const float* __restrict__ W2,
                            ushort_t* __restrict__ Wt1, ushort_t* __restrict__ Wt2,
                            float* __restrict__ cvec, float* __restrict__ czero) {
  __shared__ float mn_s[128], s_s[128];
  int j = threadIdx.x;
  float mn = decf(minenc[j]);
  float mx = decf(maxenc[j]);
  float denom = (mx > mn) ? (mx - mn) : 1.0f;
  mn_s[j] = mn; s_s[j] = 1.0f / denom;
  __syncthreads();
  float c = 0.f;
  for (int k = 0; k < 128; ++k) {
    float wp = s_s[k] * W1[k * 128 + j];
    ushort_t wb = f2bf(wp);
    Wt1[j * 128 + k] = wb;
    c += mn_s[k] * bf2f(wb);  // fold against the ROUNDED weight so it cancels
    Wt2[j * 128 + k] = f2bf(W2[k * 128 + j]);
  }
  cvec[j] = c;
  czero[j] = 0.f;
}

__global__ void deg_kernel(const void* __restrict__ edges, int E,
                           const int* __restrict__ flag64, int* __restrict__ deg) {
  int e = blockIdx.x * blockDim.x + threadIdx.x;
  if (e >= E) return;
  int is64 = *flag64;
  int s, d;
  load_edge(edges, E, e, is64, s, d);
  atomicAdd(&deg[d], 1);
}

__global__ void dinv_kernel(const int* __restrict__ deg, float* __restrict__ dinv, int N) {
  int i = blockIdx.x * blockDim.x + threadIdx.x;
  if (i < N) dinv[i] = rsqrtf((float)deg[i] + 1.0f);  // +1 = self loop
}

// ---- prefix scan: deg -> rowptr (exclusive) --------------------------------
#define SB 256

__global__ void scan1_kernel(const int* __restrict__ deg, int* __restrict__ rowptr,
                             int* __restrict__ bsum, int N) {
  __shared__ int tmp[SB];
  int i = blockIdx.x * SB + threadIdx.x;
  int v = (i < N) ? deg[i] : 0;
  tmp[threadIdx.x] = v;
  __syncthreads();
  for (int off = 1; off < SB; off <<= 1) {
    int t = (threadIdx.x >= off) ? tmp[threadIdx.x - off] : 0;
    __syncthreads();
    tmp[threadIdx.x] += t;
    __syncthreads();
  }
  if (i < N) rowptr[i] = tmp[threadIdx.x] - v;
  if (threadIdx.x == 0) bsum[blockIdx.x] = tmp[SB - 1];
}

__global__ void scan2_kernel(int* __restrict__ bsum, int nb) {
  __shared__ int tmp[SB];
  int carry = 0;
  for (int base = 0; base < nb; base += SB) {
    int i = base + threadIdx.x;
    int v = (i < nb) ? bsum[i] : 0;
    tmp[threadIdx.x] = v;
    __syncthreads();
    for (int off = 1; off < SB; off <<= 1) {
      int t = (threadIdx.x >= off) ? tmp[threadIdx.x - off] : 0;
      __syncthreads();
      tmp[threadIdx.x] += t;
      __syncthreads();
    }
    if (i < nb) bsum[i] = carry + tmp[threadIdx.x] - v;
    carry += tmp[SB - 1];
    __syncthreads();
  }
}

__global__ void scan3_kernel(int* __restrict__ rowptr, int* __restrict__ cursor,
                             const int* __restrict__ bsum, int N, int E) {
  int i = blockIdx.x * SB + threadIdx.x;
  if (i < N) {
    int v = rowptr[i] + bsum[blockIdx.x];
    rowptr[i] = v;
    cursor[i] = v;
  }
  if (i == 0) rowptr[N] = E;
}

__global__ void fill_kernel(const void* __restrict__ edges, int E,
                            const int* __restrict__ flag64,
                            int* __restrict__ cursor, int* __restrict__ adj) {
  int e = blockIdx.x * blockDim.x + threadIdx.x;
  if (e >= E) return;
  int is64 = *flag64;
  int s, d;
  load_edge(edges, E, e, is64, s, d);
  int pos = atomicAdd(&cursor[d], 1);
  adj[pos] = s;
}

// ---- MFMA GEMM: g[bf16] = (X @ Wt^T - cvec) * dinv[row] --------------------
// Wt is [128 out-cols][128 k] bf16 (transposed weights). Block = 256 thr = 4
// waves; wave w computes rows blk*64+16w..+15 x all 128 cols via 8 col-tiles.
template <int XBF16>
__global__ __launch_bounds__(256) void gemm_mfma_kernel(
    const void* __restrict__ Xv, const ushort_t* __restrict__ Wtg,
    const float* __restrict__ cvec, const float* __restrict__ dinv,
    ushort_t* __restrict__ g, int N) {
  __shared__ ushort_t wt[128 * 128];  // XOR-swizzled: byte = j*256 + (k*2 ^ ((j&7)<<4))
  int t = threadIdx.x;
  for (int c = t; c < 2048; c += 256) {  // 2048 x 16B chunks
    int j = c >> 4;
    int ko = (c & 15) << 4;  // byte offset within row
    uint4 v = *(const uint4*)(Wtg + j * 128 + (ko >> 1));
    *(uint4*)((char*)wt + j * 256 + (ko ^ ((j & 7) << 4))) = v;
  }
  __syncthreads();

  int lane = t & 63, w = t >> 6;
  int lrow = lane & 15;      // A-row / B-col within fragment
  int lk = lane >> 4;        // k-group (8 bf16 each)
  int rowA = blockIdx.x * 64 + w * 16 + lrow;
  int rA = (rowA < N) ? rowA : (N - 1);

  f32x4 acc[8];
#pragma unroll
  for (int i = 0; i < 8; ++i) acc[i] = (f32x4){0.f, 0.f, 0.f, 0.f};

#pragma unroll
  for (int ks = 0; ks < 4; ++ks) {
    int k0 = ks * 32;
    bf16x8 a;
    if (XBF16) {
      a = *(const bf16x8*)((const ushort_t*)Xv + (size_t)rA * 128 + k0 + lk * 8);
    } else {
      const float* xp = (const float*)Xv + (size_t)rA * 128 + k0 + lk * 8;
      float4 f0 = *(const float4*)xp;
      float4 f1 = *(const float4*)(xp + 4);
      bf16x8 tmp;
      tmp[0] = (short)f2bf(f0.x); tmp[1] = (short)f2bf(f0.y);
      tmp[2] = (short)f2bf(f0.z); tmp[3] = (short)f2bf(f0.w);
      tmp[4] = (short)f2bf(f1.x); tmp[5] = (short)f2bf(f1.y);
      tmp[6] = (short)f2bf(f1.z); tmp[7] = (short)f2bf(f1.w);
      a = tmp;
    }
    int koff = k0 * 2 + lk * 16;
#pragma unroll
    for (int tl = 0; tl < 8; ++tl) {
      int j = tl * 16 + lrow;  // output col = Wt row
      bf16x8 b = *(const bf16x8*)((const char*)wt + j * 256 + (koff ^ ((j & 7) << 4)));
      acc[tl] = __builtin_amdgcn_mfma_f32_16x16x32_bf16(a, b, acc[tl], 0, 0, 0);
    }
  }

  int robase = blockIdx.x * 64 + w * 16 + (lane >> 4) * 4;
#pragma unroll
  for (int j = 0; j < 4; ++j) {
    int row = robase + j;
    if (row < N) {
      float dv = dinv[row];
#pragma unroll
      for (int tl = 0; tl < 8; ++tl) {
        int col = tl * 16 + lrow;
        float o = (acc[tl][j] - cvec[col]) * dv;
        g[(size_t)row * 128 + col] = f2bf(o);
      }
    }
  }
}

// ---- aggregate: 2 dst nodes per wave (32 lanes x 4 cols), pull from CSR ----
// out[d] = act(dinv[d] * (g[d] + sum_{s in adj[d]} g[s]) + b)
template <int LAYER2>
__global__ __launch_bounds__(256) void aggregate_kernel(
    const int* __restrict__ rowptr, const int* __restrict__ adj,
    const ushort_t* __restrict__ g, const float* __restrict__ dinv,
    const float* __restrict__ b, void* __restrict__ out, int N) {
  int t = blockIdx.x * blockDim.x + threadIdx.x;
  int d = t >> 5;
  if (d >= N) return;
  int lc = t & 31;  // cols lc*4 .. lc*4+3
  const ushort_t* gp = g + lc * 4;
  int beg = rowptr[d], end = rowptr[d + 1];

  ushort4 sv = *(const ushort4*)(gp + (size_t)d * 128);  // self loop
  float s0 = bf2f(sv.x), s1 = bf2f(sv.y), s2 = bf2f(sv.z), s3 = bf2f(sv.w);

  int i = beg;
  for (; i + 4 <= end; i += 4) {
    int n0 = adj[i], n1 = adj[i + 1], n2 = adj[i + 2], n3 = adj[i + 3];
    ushort4 v0 = *(const ushort4*)(gp + (size_t)n0 * 128);
    ushort4 v1 = *(const ushort4*)(gp + (size_t)n1 * 128);
    ushort4 v2 = *(const ushort4*)(gp + (size_t)n2 * 128);
    ushort4 v3 = *(const ushort4*)(gp + (size_t)n3 * 128);
    s0 += (bf2f(v0.x) + bf2f(v1.x)) + (bf2f(v2.x) + bf2f(v3.x));
    s1 += (bf2f(v0.y) + bf2f(v1.y)) + (bf2f(v2.y) + bf2f(v3.y));
    s2 += (bf2f(v0.z) + bf2f(v1.z)) + (bf2f(v2.z) + bf2f(v3.z));
    s3 += (bf2f(v0.w) + bf2f(v1.w)) + (bf2f(v2.w) + bf2f(v3.w));
  }
  for (; i < end; ++i) {
    int s = adj[i];
    ushort4 v = *(const ushort4*)(gp + (size_t)s * 128);
    s0 += bf2f(v.x); s1 += bf2f(v.y); s2 += bf2f(v.z); s3 += bf2f(v.w);
  }

  float dv = dinv[d];
  const float4 bb = *(const float4*)&b[lc * 4];
  float o0 = dv * s0 + bb.x, o1 = dv * s1 + bb.y;
  float o2 = dv * s2 + bb.z, o3 = dv * s3 + bb.w;
  if (!LAYER2) {  // relu + bf16 store
    o0 = fmaxf(o0, 0.f); o1 = fmaxf(o1, 0.f);
    o2 = fmaxf(o2, 0.f); o3 = fmaxf(o3, 0.f);
    ushort4 ov;
    ov.x = f2bf(o0); ov.y = f2bf(o1); ov.z = f2bf(o2); ov.w = f2bf(o3);
    *(ushort4*)((ushort_t*)out + (size_t)d * 128 + lc * 4) = ov;
  } else {
    float4 ov; ov.x = o0; ov.y = o1; ov.z = o2; ov.w = o3;
    *(float4*)((float*)out + (size_t)d * 128 + lc * 4) = ov;
  }
}

extern "C" void kernel_launch(void* const* d_in, const int* in_sizes, int n_in,
                              void* d_out, int out_size, void* d_ws, size_t ws_size,
                              hipStream_t stream) {
  const float* features = (const float*)d_in[0];
  const float* W1 = (const float*)d_in[1];
  const float* b1 = (const float*)d_in[2];
  const float* W2 = (const float*)d_in[3];
  const float* b2 = (const float*)d_in[4];
  const void* edges = d_in[5];
  const int N = in_sizes[0] / 128;
  const int E = in_sizes[5] / 2;
  const int NB = (N + SB - 1) / SB;

  float* ws = (float*)d_ws;
  size_t off = 0;
  ushort_t* gbuf = (ushort_t*)(ws + off);  off += (size_t)N * 64;  // bf16 N x 128
  ushort_t* h1 = (ushort_t*)(ws + off);    off += (size_t)N * 64;  // bf16 N x 128
  int* rowptr = (int*)(ws + off);      off += N + 4;
  int* cursor = (int*)(ws + off);      off += N + 4;
  int* adj = (int*)(ws + off);         off += E;
  int* deg = (int*)(ws + off);         off += N + 4;
  float* dinv = ws + off;              off += N + 4;
  int* bsum = (int*)(ws + off);        off += NB + 4;
  unsigned* minenc = (unsigned*)(ws + off); off += 128;
  unsigned* maxenc = (unsigned*)(ws + off); off += 128;
  ushort_t* Wt1 = (ushort_t*)(ws + off);    off += 128 * 64;
  ushort_t* Wt2 = (ushort_t*)(ws + off);    off += 128 * 64;
  float* cvec = ws + off;              off += 128;
  float* czero = ws + off;             off += 128;
  int* flag64 = (int*)(ws + off);      off += 4;

  float* outf = (float*)d_out;

  // ---- graph prep ----
  detect_kernel<<<1, 1, 0, stream>>>((const int*)edges, E, flag64);
  init_kernel<<<(N + 255) / 256, 256, 0, stream>>>(minenc, maxenc, deg, N);
  colminmax_kernel<<<512, 256, 0, stream>>>(features, minenc, maxenc, N);
  deg_kernel<<<(E + 255) / 256, 256, 0, stream>>>(edges, E, flag64, deg);
  prep_kernel<<<1, 128, 0, stream>>>(minenc, maxenc, W1, W2, Wt1, Wt2, cvec, czero);
  scan1_kernel<<<NB, SB, 0, stream>>>(deg, rowptr, bsum, N);
  scan2_kernel<<<1, SB, 0, stream>>>(bsum, NB);
  scan3_kernel<<<NB, SB, 0, stream>>>(rowptr, cursor, bsum, N, E);
  dinv_kernel<<<(N + 255) / 256, 256, 0, stream>>>(deg, dinv, N);
  fill_kernel<<<(E + 255) / 256, 256, 0, stream>>>(edges, E, flag64, cursor, adj);

  // ---- layer 1 ----
  gemm_mfma_kernel<0><<<(N + 63) / 64, 256, 0, stream>>>(
      features, Wt1, cvec, dinv, gbuf, N);
  aggregate_kernel<0><<<((size_t)N * 32 + 255) / 256, 256, 0, stream>>>(
      rowptr, adj, gbuf, dinv, b1, h1, N);

  // ---- layer 2 ----
  gemm_mfma_kernel<1><<<(N + 63) / 64, 256, 0, stream>>>(
      h1, Wt2, czero, dinv, gbuf, N);
  aggregate_kernel<1><<<((size_t)N * 32 + 255) / 256, 256, 0, stream>>>(
      rowptr, adj, gbuf, dinv, b2, outf, N);
}